// Round 12
// baseline (312.939 us; speedup 1.0000x reference)
//
#include <hip/hip_runtime.h>
#include <stdint.h>

// Problem constants (fixed by the reference)
#define NV    8192   // variables
#define NC    4096   // checks
#define DC    6      // edges per check
#define DV    3      // edges per variable
#define NE    24576  // edges
#define NITER 5
#define BATCH 2048

// ---------------------------------------------------------------------------
// Setup 1: per-var edge lists (sorted ascending so the np.add.at association
// and slot ranks are deterministic).
// ---------------------------------------------------------------------------

__global__ void build_v2e(const int* __restrict__ cols, int* __restrict__ cnt,
                          unsigned short* __restrict__ v2e_tmp) {
  int e = blockIdx.x * blockDim.x + threadIdx.x;
  if (e >= NE) return;
  int v = cols[e];
  int s = atomicAdd(&cnt[v], 1);
  v2e_tmp[v * DV + s] = (unsigned short)e;
}

// Setup 2: per-edge slot codes, contiguous per check: cslot[e] = k*NV + v,
// where k = rank of edge e among its var's ascending edges. (e = c*6 + j.)
__global__ void invert_slots(const unsigned short* __restrict__ v2e_tmp,
                             unsigned short* __restrict__ cslot) {
  int v = blockIdx.x * blockDim.x + threadIdx.x;
  if (v >= NV) return;
  int a = v2e_tmp[v * 3 + 0];
  int b = v2e_tmp[v * 3 + 1];
  int c = v2e_tmp[v * 3 + 2];
  int t;
  if (a > b) { t = a; a = b; b = t; }
  if (b > c) { t = b; b = c; c = t; }
  if (a > b) { t = a; a = b; b = t; }
  cslot[a] = (unsigned short)(0 * NV + v);
  cslot[b] = (unsigned short)(1 * NV + v);
  cslot[c] = (unsigned short)(2 * NV + v);
}

// ---------------------------------------------------------------------------
// Setup 3: EXACT bank schedule via bipartite edge coloring (Kempe chains).
// 256 independent problems, one per (decode-wave w, r, quarter q): 16 checks
// (lanes of the quarter) x 6 edges each, banks = var & 31, colors = rows 0..5.
// Konig: zero-conflict coloring exists whenever per-quarter bank degree <= 6
// (~97% of banks). Kempe chain: to color edge (lane l, bank b) when no color
// is free at both, take a = free-at-lane, cB = free-at-bank, walk the a/cB
// alternating path from b (never touches l — standard lemma), swap colors
// along it, then color (l,b) with a. Chains abort (-> sticky fallback) if
// they meet a multi-occupied bank entry or exceed the cap.
// One thread per problem, all state in LDS, no atomics: DETERMINISTIC.
// Any per-check color permutation is BIT-EXACT for the decoder (check update
// is order-symmetric); a per-check validity check falls back to identity.
// ---------------------------------------------------------------------------

__global__ __launch_bounds__(64) void kempe_schedule(
    const unsigned short* __restrict__ cslot, unsigned int* __restrict__ slotp) {
  __shared__ unsigned short SL[64][96];     // slot codes
  __shared__ unsigned char EB[64][96];      // edge -> bank
  __shared__ unsigned char LE[64][16][6];   // lane x color -> edge (0xFF none)
  __shared__ unsigned char LM[64][16];      // lane color bitmask
  __shared__ unsigned char BE[64][32][6];   // bank x color -> rep edge
  __shared__ unsigned char BC[64][32][6];   // bank x color -> count
  __shared__ unsigned char CH[64][100];     // chain scratch

  const int t = threadIdx.x;
  const int pid = blockIdx.x * 64 + t;      // 0..255
  const int w = pid >> 4, r = (pid >> 2) & 3, q = pid & 3;

  const unsigned int* cs32 = (const unsigned int*)cslot;
  for (int i = 0; i < 16; ++i) {
    int c = r * 1024 + w * 64 + q * 16 + i;
    unsigned int u0 = cs32[c * 3 + 0];
    unsigned int u1 = cs32[c * 3 + 1];
    unsigned int u2 = cs32[c * 3 + 2];
    unsigned short s0 = (unsigned short)(u0 & 0xffffu), s1 = (unsigned short)(u0 >> 16);
    unsigned short s2 = (unsigned short)(u1 & 0xffffu), s3 = (unsigned short)(u1 >> 16);
    unsigned short s4 = (unsigned short)(u2 & 0xffffu), s5 = (unsigned short)(u2 >> 16);
    SL[t][i * 6 + 0] = s0; SL[t][i * 6 + 1] = s1; SL[t][i * 6 + 2] = s2;
    SL[t][i * 6 + 3] = s3; SL[t][i * 6 + 4] = s4; SL[t][i * 6 + 5] = s5;
    EB[t][i * 6 + 0] = s0 & 31; EB[t][i * 6 + 1] = s1 & 31; EB[t][i * 6 + 2] = s2 & 31;
    EB[t][i * 6 + 3] = s3 & 31; EB[t][i * 6 + 4] = s4 & 31; EB[t][i * 6 + 5] = s5 & 31;
    LM[t][i] = 0;
    for (int c2 = 0; c2 < 6; ++c2) LE[t][i][c2] = 0xFF;
  }
  for (int b = 0; b < 32; ++b)
    for (int c2 = 0; c2 < 6; ++c2) { BE[t][b][c2] = 0xFF; BC[t][b][c2] = 0; }

  for (int i = 0; i < 16; ++i) {
    for (int k = 0; k < 6; ++k) {
      const int e = i * 6 + k;
      const int b = EB[t][e];
      int freeL = (~(int)LM[t][i]) & 0x3F;
      int c = -1;
      for (int cc = 0; cc < 6; ++cc)
        if (((freeL >> cc) & 1) && BC[t][b][cc] == 0) { c = cc; break; }
      if (c < 0) {
        int a = __builtin_ctz((unsigned)freeL);
        int cB = -1;
        for (int cc = 0; cc < 6; ++cc) if (BC[t][b][cc] == 0) { cB = cc; break; }
        int done = 0;
        if (cB >= 0 && BC[t][b][a] == 1) {
          // ---- walk a/cB alternating path from bank b ----------------------
          int n = 0, ok = 1;
          int cur = BE[t][b][a];
          while (1) {
            CH[t][n++] = (unsigned char)cur;            // even pos: colored a
            int lc = (cur * 171) >> 10;                 // cur / 6
            int nxt = LE[t][lc][cB];
            if (nxt == 0xFF) break;                     // ends at lane
            if (n >= 98) { ok = 0; break; }
            CH[t][n++] = (unsigned char)nxt;            // odd pos: colored cB
            int bn = EB[t][nxt];
            if (BC[t][bn][cB] > 1) { ok = 0; break; }   // sticky rep: abort
            if (BC[t][bn][a] == 0) break;               // ends at bank
            if (BC[t][bn][a] > 1) { ok = 0; break; }
            if (n >= 98) { ok = 0; break; }
            cur = BE[t][bn][a];
          }
          if (ok) {
            // ---- flip: pass 1 clear old colors, pass 2 set swapped ---------
            for (int m = 0; m < n; ++m) {
              int e2 = CH[t][m]; int f = (m & 1) ? cB : a;
              int l2 = (e2 * 171) >> 10; int b2 = EB[t][e2];
              if (LE[t][l2][f] == e2) LE[t][l2][f] = 0xFF;
              LM[t][l2] &= ~(1 << f);
              BC[t][b2][f]--;
              if (BE[t][b2][f] == e2) BE[t][b2][f] = 0xFF;
            }
            for (int m = 0; m < n; ++m) {
              int e2 = CH[t][m]; int tt = (m & 1) ? a : cB;
              int l2 = (e2 * 171) >> 10; int b2 = EB[t][e2];
              LE[t][l2][tt] = (unsigned char)e2; LM[t][l2] |= (1 << tt);
              if (BC[t][b2][tt] == 0) BE[t][b2][tt] = (unsigned char)e2;
              BC[t][b2][tt]++;
            }
            if (LE[t][i][a] == 0xFF) { c = a; done = 1; }  // lemma holds
          }
        }
        if (!done && c < 0) {
          // sticky fallback: min-count color among lane-free colors
          freeL = (~(int)LM[t][i]) & 0x3F;
          int bcv = 256;
          for (int cc = 0; cc < 6; ++cc)
            if ((freeL >> cc) & 1) {
              int v = BC[t][b][cc];
              if (v < bcv) { bcv = v; c = cc; }
            }
        }
      }
      // place e at color c
      LE[t][i][c] = (unsigned char)e; LM[t][i] |= (1 << c);
      if (BC[t][b][c] == 0) BE[t][b][c] = (unsigned char)e;
      BC[t][b][c]++;
    }
  }

  // ---- emit (identity fallback if a lane's coloring is somehow invalid) ---
  for (int i = 0; i < 16; ++i) {
    unsigned short pm[6];
    if (LM[t][i] == 0x3F) {
      for (int c2 = 0; c2 < 6; ++c2) pm[c2] = SL[t][LE[t][i][c2]];
    } else {
      for (int c2 = 0; c2 < 6; ++c2) pm[c2] = SL[t][i * 6 + c2];
    }
    int cpos = r * 1024 + w * 64 + q * 16 + i;
    slotp[0 * NC + cpos] = (unsigned int)pm[0] | ((unsigned int)pm[1] << 16);
    slotp[1 * NC + cpos] = (unsigned int)pm[2] | ((unsigned int)pm[3] << 16);
    slotp[2 * NC + cpos] = (unsigned int)pm[4] | ((unsigned int)pm[5] << 16);
  }
}

// ---------------------------------------------------------------------------
// Fused decoder (R10-verbatim): one workgroup per batch element.
// LDS: 3 c2v planes (var-major, 96 KB) + 1 vl plane (32 KB) = 128 KB.
// c2v lives in the owning check-thread's REGISTERS across iterations.
// ---------------------------------------------------------------------------

__global__ __launch_bounds__(1024, 4) void decode_kernel(
    const float* __restrict__ ch, const float* __restrict__ wts,
    const unsigned int* __restrict__ slotp, float* __restrict__ out) {
  __shared__ float s_msg[NE];   // c2v planes, 96 KB
  __shared__ float s_vl[NV];    // var LLR plane, 32 KB

  const int tid = threadIdx.x;
  const int b = blockIdx.x;
  const float* chrow = ch + (size_t)b * NV;
  const float4* ch4 = (const float4*)chrow;

  float4 chreg[2];
  chreg[0] = ch4[tid];           // vars 4*tid .. 4*tid+3
  chreg[1] = ch4[1024 + tid];    // vars 4096+4*tid ..

  float w[NITER];
#pragma unroll
  for (int i = 0; i < NITER; ++i) w[i] = wts[i];

  // Preload slot indices (writes) and masked var indices (vl reads).
  int idx[4][6];
  int vidx[4][6];
#pragma unroll
  for (int r = 0; r < 4; ++r) {
    int c = tid + r * 1024;
    unsigned int p0 = slotp[c];
    unsigned int p1 = slotp[NC + c];
    unsigned int p2 = slotp[2 * NC + c];
    idx[r][0] = (int)(p0 & 0xFFFFu); idx[r][1] = (int)(p0 >> 16);
    idx[r][2] = (int)(p1 & 0xFFFFu); idx[r][3] = (int)(p1 >> 16);
    idx[r][4] = (int)(p2 & 0xFFFFu); idx[r][5] = (int)(p2 >> 16);
#pragma unroll
    for (int j = 0; j < 6; ++j) vidx[r][j] = idx[r][j] & (NV - 1);
  }

  // c2v for this thread's 4 checks, resident in registers across iterations.
  float creg[4][6];
#pragma unroll
  for (int r = 0; r < 4; ++r)
#pragma unroll
    for (int j = 0; j < 6; ++j) creg[r][j] = 0.0f;

  float4* m0 = (float4*)&s_msg[0];
  float4* m1 = (float4*)&s_msg[NV];
  float4* m2 = (float4*)&s_msg[2 * NV];
  float4* vl4 = (float4*)s_vl;

  // ---- init: vl = ch (it0 v2c = vl - 0 = ch) ------------------------------
#pragma unroll
  for (int p = 0; p < 2; ++p) vl4[p * 1024 + tid] = chreg[p];
  __syncthreads();

  for (int it = 0; it < NITER; ++it) {
    const float wi = w[it];

    // ---- Phase B: hoist ALL 24 vl reads (independent, pipelined) ----------
    float tv[4][6];
#pragma unroll
    for (int r = 0; r < 4; ++r)
#pragma unroll
      for (int j = 0; j < 6; ++j) tv[r][j] = s_vl[vidx[r][j]];

    // ---- Phase B compute + writes -----------------------------------------
#pragma unroll
    for (int r = 0; r < 4; ++r) {
      unsigned int u[6];
      float av[6];
      unsigned int xs = 0u;
#pragma unroll
      for (int j = 0; j < 6; ++j) {
        float t = tv[r][j] - creg[r][j];
        unsigned int uu = __float_as_uint(t);
        u[j] = uu;
        xs ^= uu;
        av[j] = __uint_as_float(uu & 0x7FFFFFFFu);
      }
      // 2-min tree: exact, order-independent (min3/med3/max)
      float m1a = fminf(fminf(av[0], av[1]), av[2]);
      float m1b = fminf(fminf(av[3], av[4]), av[5]);
      float meda = __builtin_amdgcn_fmed3f(av[0], av[1], av[2]);
      float medb = __builtin_amdgcn_fmed3f(av[3], av[4], av[5]);
      float m1v = fminf(m1a, m1b);
      float m2v = fminf(fminf(meda, medb), fmaxf(m1a, m1b));
      const bool anyz = (m1v == 0.0f);
      const float m1w = m1v * wi;
      const float m2w = m2v * wi;
#pragma unroll
      for (int j = 0; j < 6; ++j) {
        float mag = (av[j] == m1v) ? m2w : m1w;  // ties: m2v==m1v, matches ref
        unsigned int s = (xs ^ u[j]) & 0x80000000u;
        float o = __uint_as_float(__float_as_uint(mag) ^ s);
        if (anyz) o = 0.0f;
        creg[r][j] = o;
        s_msg[idx[r][j]] = o;
      }
    }
    __syncthreads();

    // ---- Phase A: vl = ch + ((c0+c1)+c2), one wide write ------------------
    if (it < NITER - 1) {
#pragma unroll
      for (int p = 0; p < 2; ++p) {
        int i4 = p * 1024 + tid;
        float4 c0 = m0[i4], c1 = m1[i4], c2 = m2[i4];
        float4 cr = chreg[p];
        float4 vl;
        vl.x = cr.x + ((c0.x + c1.x) + c2.x);   // np.add.at association
        vl.y = cr.y + ((c0.y + c1.y) + c2.y);
        vl.z = cr.z + ((c0.z + c1.z) + c2.z);
        vl.w = cr.w + ((c0.w + c1.w) + c2.w);
        vl4[i4] = vl;
      }
      __syncthreads();
    }
  }

  // ---- Final: out = ch + ((c0+c1)+c2), float4 stores ----------------------
  float4* orow4 = (float4*)(out + (size_t)b * NV);
#pragma unroll
  for (int p = 0; p < 2; ++p) {
    int i4 = p * 1024 + tid;
    float4 c0 = m0[i4], c1 = m1[i4], c2 = m2[i4];
    float4 cr = chreg[p];
    float4 o;
    o.x = cr.x + ((c0.x + c1.x) + c2.x);
    o.y = cr.y + ((c0.y + c1.y) + c2.y);
    o.z = cr.z + ((c0.z + c1.z) + c2.z);
    o.w = cr.w + ((c0.w + c1.w) + c2.w);
    orow4[i4] = o;
  }
}

// ---------------------------------------------------------------------------

extern "C" void kernel_launch(void* const* d_in, const int* in_sizes, int n_in,
                              void* d_out, int out_size, void* d_ws, size_t ws_size,
                              hipStream_t stream) {
  (void)in_sizes; (void)n_in; (void)out_size; (void)ws_size;

  const float* ch   = (const float*)d_in[0];   // [BATCH, NV] f32
  const float* wts  = (const float*)d_in[1];   // [NITER, 1] f32
  const int*  Hcols = (const int*)d_in[3];     // [NE] i32
  float* out = (float*)d_out;

  char* ws = (char*)d_ws;
  int*            cnt     = (int*)(ws + 0);                  // 32768 B
  unsigned short* v2e_tmp = (unsigned short*)(ws + 32768);   // 49152 B
  unsigned short* cslot   = (unsigned short*)(ws + 81920);   // 49152 B
  unsigned int*   slotp   = (unsigned int*)(ws + 131072);    // 49152 B
  // total ws use: 180224 B

  hipMemsetAsync(cnt, 0, NV * sizeof(int), stream);
  build_v2e<<<(NE + 255) / 256, 256, 0, stream>>>(Hcols, cnt, v2e_tmp);
  invert_slots<<<(NV + 255) / 256, 256, 0, stream>>>(v2e_tmp, cslot);
  kempe_schedule<<<4, 64, 0, stream>>>(cslot, slotp);

  decode_kernel<<<BATCH, 1024, 0, stream>>>(ch, wts, slotp, out);
}